// Round 1
// baseline (59.854 us; speedup 1.0000x reference)
//
#include <hip/hip_runtime.h>

// Grouped width-conv (2 groups x 12ch, k=7, same-pad, shared weights) + roll(+1,h).
// x: (1,24,112,112) f32, W: (12,12,7) f32 as W[i][oc][j]; out f32 (1,24,112,112).
// One block per (group, h_out). Block 384 = 6 waves.
//   - Stage 12 input rows (h_src = h_out-1 mod 112) into LDS, padded 4 floats each side
//     (pad=4 keeps every LDS access 16B-aligned; taps need only 3).
//   - Stage W transposed as ws[oc][i][8] (7 taps + 1 zero pad) in LDS.
//   - Threads 0..335: oc = tid/28, w_base = 4*(tid%28); 4 outputs each.
//     Per i: 3x ds_read_b128 (x sliding window) + 2x ds_read_b128 (w, broadcast) + 28 FMA.

__global__ __launch_bounds__(384) void shiftconv_kernel(
    const float* __restrict__ x, const float* __restrict__ W, float* __restrict__ out)
{
    __shared__ float xs[12 * 120];      // row p holds x value w at p = w + 4
    __shared__ float ws[12 * 12 * 8];   // [oc][i][j], j padded to 8

    const int tid   = threadIdx.x;
    const int h_out = blockIdx.x;       // 0..111
    const int g     = blockIdx.y;       // 0..1
    const int h_src = (h_out + 111) % 112;

    // ---- stage W: 1152 entries = 384*3 ----
    #pragma unroll
    for (int k = 0; k < 3; ++k) {
        int idx = tid + 384 * k;
        int oc  = idx / 96;
        int r   = idx - oc * 96;
        int i   = r >> 3;
        int j   = r & 7;
        ws[idx] = (j < 7) ? W[(i * 12 + oc) * 7 + j] : 0.0f;
    }

    // ---- stage x: 12 rows of 112 as float4 (336 threads), zeros in pads (24 threads) ----
    if (tid < 336) {
        int i  = tid / 28;
        int c4 = (tid - i * 28) * 4;
        const float4 v = *reinterpret_cast<const float4*>(
            x + (g * 12 + i) * 12544 + h_src * 112 + c4);
        *reinterpret_cast<float4*>(&xs[i * 120 + 4 + c4]) = v;
    } else if (tid < 360) {
        int z    = tid - 336;          // 0..23
        int row  = z >> 1;
        int side = z & 1;              // 0 -> [0,4), 1 -> [116,120)
        *reinterpret_cast<float4*>(&xs[row * 120 + side * 116]) =
            make_float4(0.f, 0.f, 0.f, 0.f);
    }
    __syncthreads();

    if (tid < 336) {
        const int oc     = tid / 28;
        const int k      = tid - oc * 28;
        const int w_base = k * 4;

        float acc0 = 0.f, acc1 = 0.f, acc2 = 0.f, acc3 = 0.f;

        #pragma unroll
        for (int i = 0; i < 12; ++i) {
            const float4 xa = *reinterpret_cast<const float4*>(&xs[i * 120 + w_base]);
            const float4 xb = *reinterpret_cast<const float4*>(&xs[i * 120 + w_base + 4]);
            const float4 xc = *reinterpret_cast<const float4*>(&xs[i * 120 + w_base + 8]);
            const float xv[12] = {xa.x, xa.y, xa.z, xa.w,
                                  xb.x, xb.y, xb.z, xb.w,
                                  xc.x, xc.y, xc.z, xc.w};
            const float4 wa = *reinterpret_cast<const float4*>(&ws[(oc * 12 + i) * 8]);
            const float4 wb = *reinterpret_cast<const float4*>(&ws[(oc * 12 + i) * 8 + 4]);
            const float wv[7] = {wa.x, wa.y, wa.z, wa.w, wb.x, wb.y, wb.z};

            // xs position p = w + 4; need x at w = w_base + m + j - 3 -> xv[m + j + 1]
            #pragma unroll
            for (int j = 0; j < 7; ++j) {
                acc0 += xv[j + 1] * wv[j];
                acc1 += xv[j + 2] * wv[j];
                acc2 += xv[j + 3] * wv[j];
                acc3 += xv[j + 4] * wv[j];
            }
        }

        *reinterpret_cast<float4*>(out + (g * 12 + oc) * 12544 + h_out * 112 + w_base) =
            make_float4(acc0, acc1, acc2, acc3);
    }
}

extern "C" void kernel_launch(void* const* d_in, const int* in_sizes, int n_in,
                              void* d_out, int out_size, void* d_ws, size_t ws_size,
                              hipStream_t stream) {
    const float* x = (const float*)d_in[0];
    const float* W = (const float*)d_in[1];
    float* out     = (float*)d_out;
    shiftconv_kernel<<<dim3(112, 2), 384, 0, stream>>>(x, W, out);
}

// Round 2
// 59.186 us; speedup vs baseline: 1.0113x; 1.0113x over previous
//
#include <hip/hip_runtime.h>

// Grouped width-conv (2 groups x 12ch, k=7, same-pad, shared weights) + roll(+1,h).
// x: (1,24,112,112) f32, W: (12,12,7) f32 as W[i][oc][j]; out f32 (1,24,112,112).
// v2: one block per (h_out, g, oc_half). Block 192 = 3 waves, 8KB LDS -> multiple
// blocks co-resident per CU so barrier/staging latency of one block overlaps
// another's compute (v1 had 6-wave blocks, ~1 block/CU, unhidden barriers).
//   - Stage 12 input rows (h_src = h_out-1 mod 112) into LDS, 4-float zero pad
//     each side (16B-aligned reads; taps need only 3).
//   - Stage this half's 6 oc of W as ws[oc'][i][8] (7 taps + 1 zero pad).
//   - Threads 0..167: oc' = tid/28, w_base = 4*(tid%28); 4 outputs each.
//     Per i: 3x ds_read_b128 (x sliding window) + 2x ds_read_b128 (w) + 28 FMA.

__global__ __launch_bounds__(192) void shiftconv_kernel(
    const float* __restrict__ x, const float* __restrict__ W, float* __restrict__ out)
{
    __shared__ float xs[12 * 120];     // row p holds x value w at p = w + 4
    __shared__ float ws[6 * 12 * 8];   // [oc'][i][j], j padded to 8

    const int tid    = threadIdx.x;
    const int h_out  = blockIdx.x;     // 0..111
    const int g      = blockIdx.y;     // 0..1
    const int ochalf = blockIdx.z;     // 0..1 -> oc = ochalf*6 + oc'
    const int h_src  = (h_out + 111) % 112;

    // ---- stage W half: 576 entries = 192*3 ----
    #pragma unroll
    for (int q = 0; q < 3; ++q) {
        int idx = tid + 192 * q;       // 0..575
        int ocp = idx / 96;            // 0..5
        int r   = idx - ocp * 96;
        int i   = r >> 3;
        int j   = r & 7;
        int oc  = ochalf * 6 + ocp;
        ws[idx] = (j < 7) ? W[(i * 12 + oc) * 7 + j] : 0.0f;
    }

    // ---- stage x: 12 rows of 112 as float4 = 336 items over 192 threads (2 iters),
    //      then zero the 24 pad float4s ----
    #pragma unroll
    for (int q = 0; q < 2; ++q) {
        int idx = tid + 192 * q;       // 0..383
        if (idx < 336) {
            int i  = idx / 28;
            int c4 = (idx - i * 28) * 4;
            const float4 v = *reinterpret_cast<const float4*>(
                x + (g * 12 + i) * 12544 + h_src * 112 + c4);
            *reinterpret_cast<float4*>(&xs[i * 120 + 4 + c4]) = v;
        } else if (idx < 360) {
            int z    = idx - 336;      // 0..23
            int row  = z >> 1;
            int side = z & 1;          // 0 -> [0,4), 1 -> [116,120)
            *reinterpret_cast<float4*>(&xs[row * 120 + side * 116]) =
                make_float4(0.f, 0.f, 0.f, 0.f);
        }
    }
    __syncthreads();

    if (tid < 168) {
        const int ocp    = tid / 28;             // 0..5
        const int k      = tid - ocp * 28;
        const int w_base = k * 4;
        const int oc     = ochalf * 6 + ocp;

        float acc0 = 0.f, acc1 = 0.f, acc2 = 0.f, acc3 = 0.f;

        #pragma unroll
        for (int i = 0; i < 12; ++i) {
            const float4 xa = *reinterpret_cast<const float4*>(&xs[i * 120 + w_base]);
            const float4 xb = *reinterpret_cast<const float4*>(&xs[i * 120 + w_base + 4]);
            const float4 xc = *reinterpret_cast<const float4*>(&xs[i * 120 + w_base + 8]);
            const float xv[12] = {xa.x, xa.y, xa.z, xa.w,
                                  xb.x, xb.y, xb.z, xb.w,
                                  xc.x, xc.y, xc.z, xc.w};
            const float4 wa = *reinterpret_cast<const float4*>(&ws[(ocp * 12 + i) * 8]);
            const float4 wb = *reinterpret_cast<const float4*>(&ws[(ocp * 12 + i) * 8 + 4]);
            const float wv[7] = {wa.x, wa.y, wa.z, wa.w, wb.x, wb.y, wb.z};

            // xs position p = w + 4; need x at w = w_base + m + j - 3 -> xv[m + j + 1]
            #pragma unroll
            for (int j = 0; j < 7; ++j) {
                acc0 += xv[j + 1] * wv[j];
                acc1 += xv[j + 2] * wv[j];
                acc2 += xv[j + 3] * wv[j];
                acc3 += xv[j + 4] * wv[j];
            }
        }

        *reinterpret_cast<float4*>(out + (g * 12 + oc) * 12544 + h_out * 112 + w_base) =
            make_float4(acc0, acc1, acc2, acc3);
    }
}

extern "C" void kernel_launch(void* const* d_in, const int* in_sizes, int n_in,
                              void* d_out, int out_size, void* d_ws, size_t ws_size,
                              hipStream_t stream) {
    const float* x = (const float*)d_in[0];
    const float* W = (const float*)d_in[1];
    float* out     = (float*)d_out;
    shiftconv_kernel<<<dim3(112, 2, 2), 192, 0, stream>>>(x, W, out);
}